// Round 1
// baseline (2166.361 us; speedup 1.0000x reference)
//
#include <hip/hip_runtime.h>

typedef __attribute__((ext_vector_type(8))) short short8;
typedef __attribute__((ext_vector_type(4))) float floatx4;

// Tensor layout strides (element shifts): b<<24 | c<<18 | d<<14 | h<<10 | w<<6 | p<<4 | q<<2 | r
// Axes: 0=d 1=h 2=w 3=p 4=q 5=r.  k = a*64 + c matches W.reshape(S,C,S,C) flattening.

__device__ __forceinline__ unsigned short f2bf(float f){
  unsigned int u = __float_as_uint(f);
  u += 0x7FFFu + ((u >> 16) & 1u);   // RNE
  return (unsigned short)(u >> 16);
}

template<int AX>
__device__ __forceinline__ int tidx(int m, int a, int c){
  if      (AX==0){ int b=m>>14, t=m&16383;                         return (b<<24)|(c<<18)|(a<<14)|t; }
  else if (AX==1){ int b=m>>14, d=(m>>10)&15, t=m&1023;            return (b<<24)|(c<<18)|(d<<14)|(a<<10)|t; }
  else if (AX==2){ int b=m>>14, d=(m>>10)&15, h=(m>>6)&15, t=m&63; return (b<<24)|(c<<18)|(d<<14)|(h<<10)|(a<<6)|t; }
  else if (AX==3){ int b=m>>16, dhw=(m>>4)&4095, qr=m&15;          return (b<<24)|(c<<18)|(dhw<<6)|(a<<4)|qr; }
  else if (AX==4){ int b=m>>16, dhw=(m>>4)&4095, p=(m>>2)&3, r=m&3;return (b<<24)|(c<<18)|(dhw<<6)|(p<<4)|(a<<2)|r; }
  else           { int b=m>>16, dhw=(m>>4)&4095, pq=m&15;          return (b<<24)|(c<<18)|(dhw<<6)|(pq<<2)|a; }
}

// ---------------- weight cast: fp32 [N*K] -> bf16 [N*K] ----------------
__global__ __launch_bounds__(256) void castw(const float* __restrict__ w,
                                             unsigned short* __restrict__ o, int n2){
  int tid = blockIdx.x*256 + threadIdx.x;
  if (tid < n2){
    float2 v = ((const float2*)w)[tid];
    ((unsigned int*)o)[tid] = (unsigned int)f2bf(v.x) | ((unsigned int)f2bf(v.y) << 16);
  }
}

// ---------------- pack: x (fp32, original layout) -> A[m][k] bf16 ----------------
template<int AX>
__global__ __launch_bounds__(256) void pack_ax(const float* __restrict__ x,
                                               unsigned short* __restrict__ A){
  constexpr int KHS = (AX<3) ? 9 : 7;          // log2(K/2)
  constexpr int KH  = 1 << KHS;
  int tid = blockIdx.x*256 + threadIdx.x;       // over M*K/2 = 16,777,216
  int kh = tid & (KH-1);
  int m  = tid >> KHS;
  int k  = kh*2;                                // c even -> c+1 stays in same a
  int s0 = tidx<AX>(m, k>>6, k&63);
  float f0 = x[s0];
  float f1 = x[s0 + (1<<18)];                   // c+1
  ((unsigned int*)A)[tid] = (unsigned int)f2bf(f0) | ((unsigned int)f2bf(f1) << 16);
}

// ---------------- GEMM: out[n=(a',c'), m] (+)= sum_k W[n][k] * A[m][k] ----------------
// MFMA-A := weight rows (n), MFMA-B := x rows (m)  -> D col(lane&15) = m = memory-contiguous
template<int AX, bool FIRST>
__global__ __launch_bounds__(256) void gemm_ax(const unsigned short* __restrict__ Apk,
                                               const unsigned short* __restrict__ Wbf,
                                               float* __restrict__ out){
  constexpr int K  = (AX<3) ? 1024 : 256;
  constexpr int NT = (AX<3) ? 8 : 2;            // N/128
  int mt = blockIdx.x / NT;
  int nt = blockIdx.x % NT;

  __shared__ unsigned short Xs[128*40];         // 32 k + 8 pad shorts -> 80B rows (2-way only)
  __shared__ unsigned short Ws[128*40];

  int t = threadIdx.x, lane = t & 63, wid = t >> 6;
  int wn = (wid & 1) << 6;                      // weight-row quadrant
  int wm = (wid >> 1) << 6;                     // x-row quadrant
  int q = lane >> 4, l16 = lane & 15;

  floatx4 acc[4][4];
  #pragma unroll
  for (int i=0;i<4;i++)
    #pragma unroll
    for (int j=0;j<4;j++) acc[i][j] = (floatx4){0.f,0.f,0.f,0.f};

  const unsigned short* Ap = Apk + (size_t)mt*128*K;
  const unsigned short* Wp = Wbf + (size_t)nt*128*K;

  int ch0 = t, ch1 = t + 256;                   // 512 16B-chunks per tile
  int r0 = ch0 >> 2, p0 = ch0 & 3;
  int r1 = ch1 >> 2, p1 = ch1 & 3;

  for (int k0 = 0; k0 < K; k0 += 32){
    uint4 a0 = *(const uint4*)(Ap + (size_t)r0*K + k0 + p0*8);
    uint4 a1 = *(const uint4*)(Ap + (size_t)r1*K + k0 + p1*8);
    uint4 b0 = *(const uint4*)(Wp + (size_t)r0*K + k0 + p0*8);
    uint4 b1 = *(const uint4*)(Wp + (size_t)r1*K + k0 + p1*8);
    *(uint4*)&Xs[r0*40 + p0*8] = a0;
    *(uint4*)&Xs[r1*40 + p1*8] = a1;
    *(uint4*)&Ws[r0*40 + p0*8] = b0;
    *(uint4*)&Ws[r1*40 + p1*8] = b1;
    __syncthreads();

    short8 wf[4], xf[4];
    #pragma unroll
    for (int i=0;i<4;i++){
      wf[i] = *(const short8*)&Ws[(wn + i*16 + l16)*40 + q*8];
      xf[i] = *(const short8*)&Xs[(wm + i*16 + l16)*40 + q*8];
    }
    #pragma unroll
    for (int i=0;i<4;i++)
      #pragma unroll
      for (int j=0;j<4;j++)
        acc[i][j] = __builtin_amdgcn_mfma_f32_16x16x32_bf16(wf[i], xf[j], acc[i][j], 0,0,0);
    __syncthreads();
  }

  #pragma unroll
  for (int i=0;i<4;i++){
    #pragma unroll
    for (int j=0;j<4;j++){
      int mg = mt*128 + wm + j*16 + l16;
      #pragma unroll
      for (int rg=0; rg<4; rg++){
        int ng = nt*128 + wn + i*16 + q*4 + rg;
        int idx = tidx<AX>(mg, ng>>6, ng&63);
        if (FIRST) out[idx]  = acc[i][j][rg];
        else       out[idx] += acc[i][j][rg];
      }
    }
  }
}

// ---------------- epilogue: out = x + leaky(out + total_bias) ----------------
__global__ __launch_bounds__(256) void epilogue_k(const float* __restrict__ x,
                                                  float* __restrict__ out,
                                                  const float* __restrict__ bd,
                                                  const float* __restrict__ bh,
                                                  const float* __restrict__ bw,
                                                  const float* __restrict__ bpd,
                                                  const float* __restrict__ bph,
                                                  const float* __restrict__ bpw){
  int tid = blockIdx.x*256 + threadIdx.x;       // over 8,388,608 (4 elems each)
  int base = tid * 4;
  int c = (base>>18)&63, d = (base>>14)&15, h = (base>>10)&15;
  int w = (base>>6)&15,  p = (base>>4)&3,  qq = (base>>2)&3;
  float bias0 = bd[d*64+c] + bh[h*64+c] + bw[w*64+c] + bpd[p*64+c] + bph[qq*64+c];
  float4 o  = *(float4*)(out + base);
  float4 xv = *(const float4*)(x + base);
  float y;
  y = o.x + bias0 + bpw[0*64+c]; o.x = xv.x + (y >= 0.f ? y : 0.01f*y);
  y = o.y + bias0 + bpw[1*64+c]; o.y = xv.y + (y >= 0.f ? y : 0.01f*y);
  y = o.z + bias0 + bpw[2*64+c]; o.z = xv.z + (y >= 0.f ? y : 0.01f*y);
  y = o.w + bias0 + bpw[3*64+c]; o.w = xv.w + (y >= 0.f ? y : 0.01f*y);
  *(float4*)(out + base) = o;
}

// ---------------- host-side dispatch ----------------
static void launch_pack(int ax, const float* x, unsigned short* buf, hipStream_t s){
  switch(ax){
    case 0: pack_ax<0><<<65536,256,0,s>>>(x,buf); break;
    case 1: pack_ax<1><<<65536,256,0,s>>>(x,buf); break;
    case 2: pack_ax<2><<<65536,256,0,s>>>(x,buf); break;
    case 3: pack_ax<3><<<65536,256,0,s>>>(x,buf); break;
    case 4: pack_ax<4><<<65536,256,0,s>>>(x,buf); break;
    case 5: pack_ax<5><<<65536,256,0,s>>>(x,buf); break;
  }
}

static void launch_gemm(int ax, bool first, const unsigned short* A, const unsigned short* W,
                        float* out, hipStream_t s){
  if (first){
    switch(ax){
      case 0: gemm_ax<0,true><<<2048,256,0,s>>>(A,W,out); break;
      case 1: gemm_ax<1,true><<<2048,256,0,s>>>(A,W,out); break;
      case 2: gemm_ax<2,true><<<2048,256,0,s>>>(A,W,out); break;
      case 3: gemm_ax<3,true><<<2048,256,0,s>>>(A,W,out); break;
      case 4: gemm_ax<4,true><<<2048,256,0,s>>>(A,W,out); break;
      case 5: gemm_ax<5,true><<<2048,256,0,s>>>(A,W,out); break;
    }
  } else {
    switch(ax){
      case 0: gemm_ax<0,false><<<2048,256,0,s>>>(A,W,out); break;
      case 1: gemm_ax<1,false><<<2048,256,0,s>>>(A,W,out); break;
      case 2: gemm_ax<2,false><<<2048,256,0,s>>>(A,W,out); break;
      case 3: gemm_ax<3,false><<<2048,256,0,s>>>(A,W,out); break;
      case 4: gemm_ax<4,false><<<2048,256,0,s>>>(A,W,out); break;
      case 5: gemm_ax<5,false><<<2048,256,0,s>>>(A,W,out); break;
    }
  }
}

extern "C" void kernel_launch(void* const* d_in, const int* in_sizes, int n_in,
                              void* d_out, int out_size, void* d_ws, size_t ws_size,
                              hipStream_t stream){
  const float* x = (const float*)d_in[0];
  const float* Wsrc[6] = {(const float*)d_in[1], (const float*)d_in[3], (const float*)d_in[5],
                          (const float*)d_in[7], (const float*)d_in[9], (const float*)d_in[11]};
  const float* Bsrc[6] = {(const float*)d_in[2], (const float*)d_in[4], (const float*)d_in[6],
                          (const float*)d_in[8], (const float*)d_in[10], (const float*)d_in[12]};
  float* out = (float*)d_out;
  char* ws = (char*)d_ws;

  const size_t welems[6] = {1024u*1024u, 1024u*1024u, 1024u*1024u,
                            256u*256u, 256u*256u, 256u*256u};
  size_t wOff[6], o = 0;
  for (int i=0;i<6;i++){ wOff[i] = o; o += welems[i]*2; }
  size_t packBase = (o + 255) & ~(size_t)255;
  const size_t PACKB = (size_t)33554432 * 2;    // 64 MiB per axis pack

  long avail = (long)((ws_size > packBase) ? (ws_size - packBase) / PACKB : 0);
  int P = (int)(avail < 1 ? 1 : (avail > 6 ? 6 : avail));  // hope ws >= ~74 MiB

  // cast weights to bf16
  for (int i=0;i<6;i++){
    int n2 = (int)(welems[i]/2);
    castw<<<(n2+255)/256,256,0,stream>>>(Wsrc[i], (unsigned short*)(ws + wOff[i]), n2);
  }

  bool first = true;
  for (int g=0; g<6; g+=P){
    int e = (g+P < 6) ? g+P : 6;
    for (int i=g; i<e; i++)
      launch_pack(i, x, (unsigned short*)(ws + packBase + (size_t)(i-g)*PACKB), stream);
    for (int i=g; i<e; i++){
      launch_gemm(i, first, (unsigned short*)(ws + packBase + (size_t)(i-g)*PACKB),
                  (unsigned short*)(ws + wOff[i]), out, stream);
      first = false;
    }
  }

  epilogue_k<<<32768,256,0,stream>>>(x, out, Bsrc[0], Bsrc[1], Bsrc[2], Bsrc[3], Bsrc[4], Bsrc[5]);
}

// Round 2
// 1079.153 us; speedup vs baseline: 2.0075x; 2.0075x over previous
//
#include <hip/hip_runtime.h>

typedef __attribute__((ext_vector_type(8))) short short8;
typedef __attribute__((ext_vector_type(4))) float floatx4;

// Original x layout (element offsets): b<<24 | c<<18 | d<<14 | h<<10 | w<<6 | p<<4 | q<<2 | r
// Transposed xT layout (bf16):         b<<24 | d<<20 | h<<16 | w<<12 | p<<10 | q<<8 | r<<6 | c
//   i.e. xT offset = b<<24 | s<<6 | c  with s = d<<14|h<<10|w<<6|p<<4|q<<2|r (same packing).
// Axes: 0=d 1=h 2=w 3=p 4=q 5=r.  GEMM k = a*64 + c (matches W.reshape(S,C,S,C)).

__device__ __forceinline__ unsigned short f2bf(float f){
  unsigned int u = __float_as_uint(f);
  u += 0x7FFFu + ((u >> 16) & 1u);   // RNE
  return (unsigned short)(u >> 16);
}

// m -> element offset in ORIGINAL layout, given axis value a and channel c (for stores)
template<int AX>
__device__ __forceinline__ int tidx(int m, int a, int c){
  if      (AX==0){ int b=m>>14, t=m&16383;                         return (b<<24)|(c<<18)|(a<<14)|t; }
  else if (AX==1){ int b=m>>14, d=(m>>10)&15, t=m&1023;            return (b<<24)|(c<<18)|(d<<14)|(a<<10)|t; }
  else if (AX==2){ int b=m>>14, d=(m>>10)&15, h=(m>>6)&15, t=m&63; return (b<<24)|(c<<18)|(d<<14)|(h<<10)|(a<<6)|t; }
  else if (AX==3){ int b=m>>16, dhw=(m>>4)&4095, qr=m&15;          return (b<<24)|(c<<18)|(dhw<<6)|(a<<4)|qr; }
  else if (AX==4){ int b=m>>16, dhw=(m>>4)&4095, p=(m>>2)&3, r=m&3;return (b<<24)|(c<<18)|(dhw<<6)|(p<<4)|(a<<2)|r; }
  else           { int b=m>>16, dhw=(m>>4)&4095, pq=m&15;          return (b<<24)|(c<<18)|(dhw<<6)|(pq<<2)|a; }
}

// m -> base element offset in TRANSPOSED layout (a=0, c=0); add a*SA + c.
template<int AX>
__device__ __forceinline__ int srcbase(int m){
  if      (AX==0) return ((m>>14)<<24) | (((m>>10)&15)<<16) | (((m>>6)&15)<<12) | ((m&63)<<6);
  else if (AX==1) return ((m>>14)<<24) | (((m>>10)&15)<<20) | (((m>>6)&15)<<12) | ((m&63)<<6);
  else if (AX==2) return ((m>>14)<<24) | (((m>>10)&15)<<20) | (((m>>6)&15)<<16) | ((m&63)<<6);
  else if (AX==3) return ((m>>16)<<24) | (((m>>4)&4095)<<12) | ((m&15)<<6);
  else if (AX==4) return ((m>>16)<<24) | (((m>>4)&4095)<<12) | (((m>>2)&3)<<10) | ((m&3)<<6);
  else            return ((m>>16)<<24) | (((m>>4)&4095)<<12) | (((m>>2)&3)<<10) | ((m&3)<<8);
}

// ---------------- fused weight cast: 6 × fp32 [N*K] -> bf16 ----------------
__global__ __launch_bounds__(256) void castw_all(
    const float* __restrict__ wa, const float* __restrict__ wb, const float* __restrict__ wc,
    const float* __restrict__ wd_, const float* __restrict__ we, const float* __restrict__ wf,
    unsigned short* oa, unsigned short* ob, unsigned short* oc,
    unsigned short* od, unsigned short* oe, unsigned short* of_){
  int blk = blockIdx.x;
  const float* src; unsigned short* dst; int idx;
  if (blk < 6144){ int wsel = blk >> 11, loc = blk & 2047;
    src = wsel==0?wa:(wsel==1?wb:wc); dst = wsel==0?oa:(wsel==1?ob:oc);
    idx = loc*256 + threadIdx.x; }
  else { int b2 = blk - 6144, wsel = b2 >> 7, loc = b2 & 127;
    src = wsel==0?wd_:(wsel==1?we:wf); dst = wsel==0?od:(wsel==1?oe:of_);
    idx = loc*256 + threadIdx.x; }
  float2 v = ((const float2*)src)[idx];
  ((unsigned int*)dst)[idx] = (unsigned int)f2bf(v.x) | ((unsigned int)f2bf(v.y) << 16);
}

// ---------------- transpose: x fp32 [b][c][s] -> xT bf16 [b][s][c] ----------------
__global__ __launch_bounds__(256) void transpose_cx(const float* __restrict__ x,
                                                    unsigned short* __restrict__ xt){
  __shared__ float T[64][65];
  int b  = blockIdx.x >> 12;
  int s0 = (blockIdx.x & 4095) * 64;
  int t = threadIdx.x;
  int cr = t >> 4, sq = t & 15;            // read: 16 c-rows x 16 float4 per pass
  #pragma unroll
  for (int it = 0; it < 4; it++){
    int c = it*16 + cr;
    float4 v = *(const float4*)(x + (b<<24) + (c<<18) + s0 + sq*4);
    T[c][sq*4+0]=v.x; T[c][sq*4+1]=v.y; T[c][sq*4+2]=v.z; T[c][sq*4+3]=v.w;
  }
  __syncthreads();
  int sw = t >> 2, cq = t & 3;             // write: each thread 16 c of one s (32B)
  unsigned int pk[8];
  #pragma unroll
  for (int i=0;i<8;i++){
    float f0 = T[cq*16 + 2*i    ][sw];
    float f1 = T[cq*16 + 2*i + 1][sw];
    pk[i] = (unsigned int)f2bf(f0) | ((unsigned int)f2bf(f1) << 16);
  }
  uint4* dst = (uint4*)(xt + (b<<24) + ((s0 + sw)<<6) + cq*16);
  dst[0] = make_uint4(pk[0],pk[1],pk[2],pk[3]);
  dst[1] = make_uint4(pk[4],pk[5],pk[6],pk[7]);
}

// ---------------- GEMM: out[n=(a',c'), m] (+)= sum_k W[n][k] * xT[m][k] ----------------
// MFMA-A := weight rows (n), MFMA-B := x rows (m) -> D col(lane&15) = m (contig stores)
template<int AX, bool FIRST>
__global__ __launch_bounds__(256) void gemm_ax(const unsigned short* __restrict__ xt,
                                               const unsigned short* __restrict__ Wbf,
                                               float* __restrict__ out){
  constexpr int K  = (AX<3) ? 1024 : 256;
  constexpr int NT = (AX<3) ? 8 : 2;            // N/128
  constexpr int SA = (AX==0)?(1<<20):(AX==1)?(1<<16):(AX==2)?(1<<12)
                    :(AX==3)?(1<<10):(AX==4)?(1<<8):(1<<6);
  int mt = blockIdx.x / NT;
  int nt = blockIdx.x % NT;

  __shared__ unsigned short Xs[128*40];         // 32 k + 8 pad shorts -> 80B rows
  __shared__ unsigned short Ws[128*40];

  int t = threadIdx.x, lane = t & 63, wid = t >> 6;
  int wn = (wid & 1) << 6;
  int wm = (wid >> 1) << 6;
  int q = lane >> 4, l16 = lane & 15;

  floatx4 acc[4][4];
  #pragma unroll
  for (int i=0;i<4;i++)
    #pragma unroll
    for (int j=0;j<4;j++) acc[i][j] = (floatx4){0.f,0.f,0.f,0.f};

  const unsigned short* Wp = Wbf + (size_t)nt*128*K;

  int r0 = t >> 2, p0 = t & 3;                  // X/W chunk coords (2 chunks each)
  int base0 = srcbase<AX>(mt*128 + r0);
  int base1 = srcbase<AX>(mt*128 + 64 + r0);

  for (int k0 = 0; k0 < K; k0 += 32){
    int aK = k0 >> 6, c0 = k0 & 63;
    const unsigned short* xa = xt + aK*SA + c0 + p0*8;
    uint4 a0 = *(const uint4*)(xa + base0);
    uint4 a1 = *(const uint4*)(xa + base1);
    uint4 b0 = *(const uint4*)(Wp + (size_t)r0*K      + k0 + p0*8);
    uint4 b1 = *(const uint4*)(Wp + (size_t)(r0+64)*K + k0 + p0*8);
    *(uint4*)&Xs[r0*40      + p0*8] = a0;
    *(uint4*)&Xs[(r0+64)*40 + p0*8] = a1;
    *(uint4*)&Ws[r0*40      + p0*8] = b0;
    *(uint4*)&Ws[(r0+64)*40 + p0*8] = b1;
    __syncthreads();

    short8 wf[4], xf[4];
    #pragma unroll
    for (int i=0;i<4;i++){
      wf[i] = *(const short8*)&Ws[(wn + i*16 + l16)*40 + q*8];
      xf[i] = *(const short8*)&Xs[(wm + i*16 + l16)*40 + q*8];
    }
    #pragma unroll
    for (int i=0;i<4;i++)
      #pragma unroll
      for (int j=0;j<4;j++)
        acc[i][j] = __builtin_amdgcn_mfma_f32_16x16x32_bf16(wf[i], xf[j], acc[i][j], 0,0,0);
    __syncthreads();
  }

  #pragma unroll
  for (int i=0;i<4;i++){
    #pragma unroll
    for (int j=0;j<4;j++){
      int mg = mt*128 + wm + j*16 + l16;
      #pragma unroll
      for (int rg=0; rg<4; rg++){
        int ng = nt*128 + wn + i*16 + q*4 + rg;
        int idx = tidx<AX>(mg, ng>>6, ng&63);
        if (FIRST) out[idx]  = acc[i][j][rg];
        else       out[idx] += acc[i][j][rg];
      }
    }
  }
}

// ---------------- epilogue: out = x + leaky(out + total_bias) ----------------
__global__ __launch_bounds__(256) void epilogue_k(const float* __restrict__ x,
                                                  float* __restrict__ out,
                                                  const float* __restrict__ bd,
                                                  const float* __restrict__ bh,
                                                  const float* __restrict__ bw,
                                                  const float* __restrict__ bpd,
                                                  const float* __restrict__ bph,
                                                  const float* __restrict__ bpw){
  int tid = blockIdx.x*256 + threadIdx.x;
  int base = tid * 4;
  int c = (base>>18)&63, d = (base>>14)&15, h = (base>>10)&15;
  int w = (base>>6)&15,  p = (base>>4)&3,  qq = (base>>2)&3;
  float bias0 = bd[d*64+c] + bh[h*64+c] + bw[w*64+c] + bpd[p*64+c] + bph[qq*64+c];
  float4 o  = *(float4*)(out + base);
  float4 xv = *(const float4*)(x + base);
  float y;
  y = o.x + bias0 + bpw[0*64+c]; o.x = xv.x + (y >= 0.f ? y : 0.01f*y);
  y = o.y + bias0 + bpw[1*64+c]; o.y = xv.y + (y >= 0.f ? y : 0.01f*y);
  y = o.z + bias0 + bpw[2*64+c]; o.z = xv.z + (y >= 0.f ? y : 0.01f*y);
  y = o.w + bias0 + bpw[3*64+c]; o.w = xv.w + (y >= 0.f ? y : 0.01f*y);
  *(float4*)(out + base) = o;
}

// ---------------- host-side dispatch ----------------
static void launch_gemm(int ax, bool first, const unsigned short* xt, const unsigned short* W,
                        float* out, hipStream_t s){
  if (first){
    switch(ax){
      case 0: gemm_ax<0,true><<<2048,256,0,s>>>(xt,W,out); break;
      case 1: gemm_ax<1,true><<<2048,256,0,s>>>(xt,W,out); break;
      case 2: gemm_ax<2,true><<<2048,256,0,s>>>(xt,W,out); break;
      case 3: gemm_ax<3,true><<<2048,256,0,s>>>(xt,W,out); break;
      case 4: gemm_ax<4,true><<<2048,256,0,s>>>(xt,W,out); break;
      case 5: gemm_ax<5,true><<<2048,256,0,s>>>(xt,W,out); break;
    }
  } else {
    switch(ax){
      case 0: gemm_ax<0,false><<<2048,256,0,s>>>(xt,W,out); break;
      case 1: gemm_ax<1,false><<<2048,256,0,s>>>(xt,W,out); break;
      case 2: gemm_ax<2,false><<<2048,256,0,s>>>(xt,W,out); break;
      case 3: gemm_ax<3,false><<<2048,256,0,s>>>(xt,W,out); break;
      case 4: gemm_ax<4,false><<<2048,256,0,s>>>(xt,W,out); break;
      case 5: gemm_ax<5,false><<<2048,256,0,s>>>(xt,W,out); break;
    }
  }
}

extern "C" void kernel_launch(void* const* d_in, const int* in_sizes, int n_in,
                              void* d_out, int out_size, void* d_ws, size_t ws_size,
                              hipStream_t stream){
  const float* x = (const float*)d_in[0];
  const float* Wsrc[6] = {(const float*)d_in[1], (const float*)d_in[3], (const float*)d_in[5],
                          (const float*)d_in[7], (const float*)d_in[9], (const float*)d_in[11]};
  const float* Bsrc[6] = {(const float*)d_in[2], (const float*)d_in[4], (const float*)d_in[6],
                          (const float*)d_in[8], (const float*)d_in[10], (const float*)d_in[12]};
  float* out = (float*)d_out;
  char* ws = (char*)d_ws;

  const size_t welems[6] = {1024u*1024u, 1024u*1024u, 1024u*1024u,
                            256u*256u, 256u*256u, 256u*256u};
  size_t wOff[6], o = 0;
  for (int i=0;i<6;i++){ wOff[i] = o; o += welems[i]*2; }
  size_t xtOff = (o + 255) & ~(size_t)255;      // 67 MiB for xT bf16
  unsigned short* xt = (unsigned short*)(ws + xtOff);
  unsigned short* Wbf[6];
  for (int i=0;i<6;i++) Wbf[i] = (unsigned short*)(ws + wOff[i]);

  castw_all<<<6528,256,0,stream>>>(Wsrc[0],Wsrc[1],Wsrc[2],Wsrc[3],Wsrc[4],Wsrc[5],
                                   Wbf[0],Wbf[1],Wbf[2],Wbf[3],Wbf[4],Wbf[5]);
  transpose_cx<<<8192,256,0,stream>>>(x, xt);

  for (int i=0;i<6;i++) launch_gemm(i, i==0, xt, Wbf[i], out, stream);

  epilogue_k<<<32768,256,0,stream>>>(x, out, Bsrc[0], Bsrc[1], Bsrc[2], Bsrc[3], Bsrc[4], Bsrc[5]);
}

// Round 3
// 953.271 us; speedup vs baseline: 2.2726x; 1.1321x over previous
//
#include <hip/hip_runtime.h>

typedef __attribute__((ext_vector_type(8))) short short8;
typedef __attribute__((ext_vector_type(4))) float floatx4;

// Original x layout (element offsets): b<<24 | c<<18 | d<<14 | h<<10 | w<<6 | p<<4 | q<<2 | r
// Transposed xT layout (bf16): offset = b<<24 | s<<6 | c, s = d<<14|...|r (same packing).
// Image axes: 0=d 1=h 2=w. Patch axes handled by patch_fused (p,q,r).
// GEMM k = a*64 + c (matches W.reshape(S,C,S,C)).

__device__ __forceinline__ unsigned short f2bf(float f){
  unsigned int u = __float_as_uint(f);
  u += 0x7FFFu + ((u >> 16) & 1u);   // RNE
  return (unsigned short)(u >> 16);
}

// m -> element offset in ORIGINAL layout, given axis value a and channel c (image stores)
template<int AX>
__device__ __forceinline__ int tidx(int m, int a, int c){
  if      (AX==0){ int b=m>>14, t=m&16383;                         return (b<<24)|(c<<18)|(a<<14)|t; }
  else if (AX==1){ int b=m>>14, d=(m>>10)&15, t=m&1023;            return (b<<24)|(c<<18)|(d<<14)|(a<<10)|t; }
  else           { int b=m>>14, d=(m>>10)&15, h=(m>>6)&15, t=m&63; return (b<<24)|(c<<18)|(d<<14)|(h<<10)|(a<<6)|t; }
}

// m -> base element offset in TRANSPOSED layout (a=0, c=0); add a*SA + c.
template<int AX>
__device__ __forceinline__ int srcbase(int m){
  if      (AX==0) return ((m>>14)<<24) | (((m>>10)&15)<<16) | (((m>>6)&15)<<12) | ((m&63)<<6);
  else if (AX==1) return ((m>>14)<<24) | (((m>>10)&15)<<20) | (((m>>6)&15)<<12) | ((m&63)<<6);
  else            return ((m>>14)<<24) | (((m>>10)&15)<<20) | (((m>>6)&15)<<16) | ((m&63)<<6);
}

#define ASYNC_CP16(g, l) \
  __builtin_amdgcn_global_load_lds( \
      (const __attribute__((address_space(1))) unsigned int*)(g), \
      (__attribute__((address_space(3))) unsigned int*)(l), 16, 0, 0)

// ---------------- fused weight cast: 6 x fp32 [N*K] -> bf16 ----------------
__global__ __launch_bounds__(256) void castw_all(
    const float* __restrict__ wa, const float* __restrict__ wb, const float* __restrict__ wc,
    const float* __restrict__ wd_, const float* __restrict__ we, const float* __restrict__ wf,
    unsigned short* oa, unsigned short* ob, unsigned short* oc,
    unsigned short* od, unsigned short* oe, unsigned short* of_){
  int blk = blockIdx.x;
  const float* src; unsigned short* dst; int idx;
  if (blk < 6144){ int wsel = blk >> 11, loc = blk & 2047;
    src = wsel==0?wa:(wsel==1?wb:wc); dst = wsel==0?oa:(wsel==1?ob:oc);
    idx = loc*256 + threadIdx.x; }
  else { int b2 = blk - 6144, wsel = b2 >> 7, loc = b2 & 127;
    src = wsel==0?wd_:(wsel==1?we:wf); dst = wsel==0?od:(wsel==1?oe:of_);
    idx = loc*256 + threadIdx.x; }
  float2 v = ((const float2*)src)[idx];
  ((unsigned int*)dst)[idx] = (unsigned int)f2bf(v.x) | ((unsigned int)f2bf(v.y) << 16);
}

// ---------------- transpose: x fp32 [b][c][s] -> xT bf16 [b][s][c] ----------------
__global__ __launch_bounds__(256) void transpose_cx(const float* __restrict__ x,
                                                    unsigned short* __restrict__ xt){
  __shared__ float T[64][65];
  int b  = blockIdx.x >> 12;
  int s0 = (blockIdx.x & 4095) * 64;
  int t = threadIdx.x;
  int cr = t >> 4, sq = t & 15;
  #pragma unroll
  for (int it = 0; it < 4; it++){
    int c = it*16 + cr;
    float4 v = *(const float4*)(x + (b<<24) + (c<<18) + s0 + sq*4);
    T[c][sq*4+0]=v.x; T[c][sq*4+1]=v.y; T[c][sq*4+2]=v.z; T[c][sq*4+3]=v.w;
  }
  __syncthreads();
  int sw = t >> 2, cq = t & 3;
  unsigned int pk[8];
  #pragma unroll
  for (int i=0;i<8;i++){
    float f0 = T[cq*16 + 2*i    ][sw];
    float f1 = T[cq*16 + 2*i + 1][sw];
    pk[i] = (unsigned int)f2bf(f0) | ((unsigned int)f2bf(f1) << 16);
  }
  uint4* dst = (uint4*)(xt + (b<<24) + ((s0 + sw)<<6) + cq*16);
  dst[0] = make_uint4(pk[0],pk[1],pk[2],pk[3]);
  dst[1] = make_uint4(pk[4],pk[5],pk[6],pk[7]);
}

// ---------------- fused patch kernel: 3 patch axes, one pass over out ----------------
// Block owns 2 consecutive patches (contiguous 8192 els of xT). Wave w owns own-axis
// output coord a'=w for each axis. LDS fp32 acc stride 65 (<=2-way banks all patterns).
template<int AXI, bool FIRST>
__device__ __forceinline__ void patch_axis(const unsigned short* __restrict__ xp,
                                           const unsigned short* __restrict__ W,
                                           float* AccL, int w, int l16, int q8){
  floatx4 acc[4][2];
  #pragma unroll
  for (int nt=0;nt<4;nt++)
    #pragma unroll
    for (int mt=0;mt<2;mt++) acc[nt][mt] = (floatx4){0.f,0.f,0.f,0.f};

  #pragma unroll 2
  for (int kit = 0; kit < 8; kit++){
    int a = kit >> 1;
    int chalf = ((kit & 1) << 5) + q8*8;
    short8 bf[2], af[4];
    int u = (AXI==0) ? (a*16 + l16)
          : (AXI==1) ? ((l16>>2)*16 + a*4 + (l16&3))
                     : ((l16>>2)*16 + (l16&3)*4 + a);
    #pragma unroll
    for (int mt = 0; mt < 2; mt++)
      bf[mt] = *(const short8*)(xp + mt*4096 + u*64 + chalf);
    #pragma unroll
    for (int nt = 0; nt < 4; nt++){
      int n = w*64 + nt*16 + l16;
      af[nt] = *(const short8*)(W + n*256 + kit*32 + q8*8);
    }
    #pragma unroll
    for (int nt=0; nt<4; nt++)
      #pragma unroll
      for (int mt=0; mt<2; mt++)
        acc[nt][mt] = __builtin_amdgcn_mfma_f32_16x16x32_bf16(af[nt], bf[mt], acc[nt][mt], 0,0,0);
  }

  int uo = (AXI==0) ? (w*16 + l16)
         : (AXI==1) ? ((l16>>2)*16 + w*4 + (l16&3))
                    : ((l16>>2)*16 + (l16&3)*4 + w);
  #pragma unroll
  for (int nt=0; nt<4; nt++)
    #pragma unroll
    for (int mt=0; mt<2; mt++){
      float* p = AccL + (mt*64 + uo)*65 + nt*16 + q8*4;
      #pragma unroll
      for (int rg=0; rg<4; rg++){
        if (FIRST) p[rg]  = acc[nt][mt][rg];
        else       p[rg] += acc[nt][mt][rg];
      }
    }
}

__global__ __launch_bounds__(256) void patch_fused(const unsigned short* __restrict__ xt,
    const unsigned short* __restrict__ Wp_, const unsigned short* __restrict__ Wq_,
    const unsigned short* __restrict__ Wr_, float* __restrict__ out){
  __shared__ float AccL[2*64*65];            // 33 KB
  int pp = blockIdx.x;
  int b = pp >> 11, dpair = pp & 2047;
  const unsigned short* xp = xt + (b<<24) + dpair*8192;
  int t = threadIdx.x, w = t>>6, lane = t&63, q8 = lane>>4, l16 = lane&15;

  patch_axis<0,true >(xp, Wp_, AccL, w, l16, q8);
  __syncthreads();
  patch_axis<1,false>(xp, Wq_, AccL, w, l16, q8);
  __syncthreads();
  patch_axis<2,false>(xp, Wr_, AccL, w, l16, q8);
  __syncthreads();

  int sbase = dpair*128;                     // s = dpair*2*64 + pt*64 + u
  #pragma unroll
  for (int it = 0; it < 32; it++){
    int lin = it*256 + t;
    int c = lin >> 7, rem = lin & 127, pt = rem >> 6, u = rem & 63;
    out[(b<<24) | (c<<18) | (sbase + pt*64 + u)] = AccL[(pt*64+u)*65 + c];
  }
}

// ---------------- image GEMM: out[n=(a',c'), m] += sum_k W[n][k] * xT[m][k] ----------------
// Async global->LDS staging (width 16), XOR chunk swizzle, always RMW into out.
template<int AX>
__global__ __launch_bounds__(256) void gemm_img(const unsigned short* __restrict__ xt,
                                                const unsigned short* __restrict__ Wbf,
                                                float* __restrict__ out){
  constexpr int K  = 1024;
  constexpr int SA = (AX==0)?(1<<20):(AX==1)?(1<<16):(1<<12);
  int mt = blockIdx.x >> 3;
  int nt = blockIdx.x & 7;

  __shared__ unsigned short Xs[128*32];      // 8 KB, rows of 64 B, chunk-swizzled
  __shared__ unsigned short Ws[128*32];

  int t = threadIdx.x, lane = t & 63, wid = t >> 6;
  int wn = (wid & 1) << 6, wm = (wid >> 1) << 6;
  int q = lane >> 4, l16 = lane & 15;

  floatx4 acc[4][4];
  #pragma unroll
  for (int i=0;i<4;i++)
    #pragma unroll
    for (int j=0;j<4;j++) acc[i][j] = (floatx4){0.f,0.f,0.f,0.f};

  const unsigned short* Wp = Wbf + (size_t)nt*128*K;

  // staging constants: chunk c = call*256 + t; row = c>>2; global k-chunk jj = (c&3)^((c>>3)&3)
  int row = t >> 2;
  int jj  = (t & 3) ^ ((t >> 3) & 3);
  int base0 = srcbase<AX>(mt*128 + row);
  int base1 = srcbase<AX>(mt*128 + 64 + row);
  const unsigned short* wg0 = Wp + row*K + jj*8;
  const unsigned short* wg1 = Wp + (row+64)*K + jj*8;
  unsigned short* ldsX0 = Xs + wid*512;          // wave-uniform bases (lane*16 appended by HW)
  unsigned short* ldsX1 = Xs + 2048 + wid*512;
  unsigned short* ldsW0 = Ws + wid*512;
  unsigned short* ldsW1 = Ws + 2048 + wid*512;

  // frag LDS byte->short offsets (swizzled), fixed across K
  int xoff[4], woff[4];
  #pragma unroll
  for (int i=0;i<4;i++){
    int rx = wm + i*16 + l16; xoff[i] = rx*32 + ((q ^ ((rx>>1)&3))<<3);
    int rw = wn + i*16 + l16; woff[i] = rw*32 + ((q ^ ((rw>>1)&3))<<3);
  }

  for (int k0 = 0; k0 < K; k0 += 32){
    int aK = k0 >> 6;
    int cc = (k0 & 63) + jj*8;
    ASYNC_CP16(xt + base0 + aK*SA + cc, ldsX0);
    ASYNC_CP16(xt + base1 + aK*SA + cc, ldsX1);
    ASYNC_CP16(wg0 + k0, ldsW0);
    ASYNC_CP16(wg1 + k0, ldsW1);
    __syncthreads();

    short8 wf[4], xf[4];
    #pragma unroll
    for (int i=0;i<4;i++){
      wf[i] = *(const short8*)&Ws[woff[i]];
      xf[i] = *(const short8*)&Xs[xoff[i]];
    }
    #pragma unroll
    for (int i=0;i<4;i++)
      #pragma unroll
      for (int j=0;j<4;j++)
        acc[i][j] = __builtin_amdgcn_mfma_f32_16x16x32_bf16(wf[i], xf[j], acc[i][j], 0,0,0);
    __syncthreads();
  }

  #pragma unroll
  for (int i=0;i<4;i++){
    #pragma unroll
    for (int j=0;j<4;j++){
      int mg = mt*128 + wm + j*16 + l16;
      #pragma unroll
      for (int rg=0; rg<4; rg++){
        int ng = nt*128 + wn + i*16 + q*4 + rg;
        int idx = tidx<AX>(mg, ng>>6, ng&63);
        out[idx] += acc[i][j][rg];
      }
    }
  }
}

// ---------------- epilogue: out = x + leaky(out + total_bias), in place ----------------
__global__ __launch_bounds__(256) void epilogue_k(const float* __restrict__ x,
                                                  float* __restrict__ out,
                                                  const float* __restrict__ bd,
                                                  const float* __restrict__ bh,
                                                  const float* __restrict__ bw,
                                                  const float* __restrict__ bpd,
                                                  const float* __restrict__ bph,
                                                  const float* __restrict__ bpw){
  int tid = blockIdx.x*256 + threadIdx.x;
  int base = tid * 4;
  int c = (base>>18)&63, d = (base>>14)&15, h = (base>>10)&15;
  int w = (base>>6)&15,  p = (base>>4)&3,  qq = (base>>2)&3;
  float bias0 = bd[d*64+c] + bh[h*64+c] + bw[w*64+c] + bpd[p*64+c] + bph[qq*64+c];
  float4 o  = *(float4*)(out + base);
  float4 xv = *(const float4*)(x + base);
  float y;
  y = o.x + bias0 + bpw[0*64+c]; o.x = xv.x + (y >= 0.f ? y : 0.01f*y);
  y = o.y + bias0 + bpw[1*64+c]; o.y = xv.y + (y >= 0.f ? y : 0.01f*y);
  y = o.z + bias0 + bpw[2*64+c]; o.z = xv.z + (y >= 0.f ? y : 0.01f*y);
  y = o.w + bias0 + bpw[3*64+c]; o.w = xv.w + (y >= 0.f ? y : 0.01f*y);
  *(float4*)(out + base) = o;
}

// ---------------- host-side dispatch ----------------
extern "C" void kernel_launch(void* const* d_in, const int* in_sizes, int n_in,
                              void* d_out, int out_size, void* d_ws, size_t ws_size,
                              hipStream_t stream){
  const float* x = (const float*)d_in[0];
  const float* Wsrc[6] = {(const float*)d_in[1], (const float*)d_in[3], (const float*)d_in[5],
                          (const float*)d_in[7], (const float*)d_in[9], (const float*)d_in[11]};
  const float* Bsrc[6] = {(const float*)d_in[2], (const float*)d_in[4], (const float*)d_in[6],
                          (const float*)d_in[8], (const float*)d_in[10], (const float*)d_in[12]};
  float* out = (float*)d_out;
  char* ws = (char*)d_ws;

  const size_t welems[6] = {1024u*1024u, 1024u*1024u, 1024u*1024u,
                            256u*256u, 256u*256u, 256u*256u};
  size_t wOff[6], o = 0;
  for (int i=0;i<6;i++){ wOff[i] = o; o += welems[i]*2; }
  size_t xtOff = (o + 255) & ~(size_t)255;      // 64 MiB for xT bf16
  unsigned short* xt = (unsigned short*)(ws + xtOff);
  unsigned short* Wbf[6];
  for (int i=0;i<6;i++) Wbf[i] = (unsigned short*)(ws + wOff[i]);

  castw_all<<<6528,256,0,stream>>>(Wsrc[0],Wsrc[1],Wsrc[2],Wsrc[3],Wsrc[4],Wsrc[5],
                                   Wbf[0],Wbf[1],Wbf[2],Wbf[3],Wbf[4],Wbf[5]);
  transpose_cx<<<8192,256,0,stream>>>(x, xt);

  // patches first: single full write of out (3 patch axes fused)
  patch_fused<<<4096,256,0,stream>>>(xt, Wbf[3], Wbf[4], Wbf[5], out);

  // image axes: RMW into out
  gemm_img<0><<<2048,256,0,stream>>>(xt, Wbf[0], out);
  gemm_img<1><<<2048,256,0,stream>>>(xt, Wbf[1], out);
  gemm_img<2><<<2048,256,0,stream>>>(xt, Wbf[2], out);

  epilogue_k<<<32768,256,0,stream>>>(x, out, Bsrc[0], Bsrc[1], Bsrc[2], Bsrc[3], Bsrc[4], Bsrc[5]);
}